// Round 3
// baseline (373.341 us; speedup 1.0000x reference)
//
#include <hip/hip_runtime.h>
#include <math.h>

// Native clang vector type — required for __builtin_nontemporal_store
// (HIP's float4 is a class and is rejected by the builtin).
typedef float f32x4 __attribute__((ext_vector_type(4)));

// Toggle if correctness feedback indicates XLA fused tau*m+ic into an FMA.
#ifndef USE_FMA
#define USE_FMA 0
#endif

__device__ __forceinline__ float step_madd(float tau, float m, float ic) {
#if USE_FMA
    return __fmaf_rn(tau, m, ic);
#else
    // Separate mul/add, IEEE round-to-nearest, no contraction — matches XLA's
    // distinct fmul/fadd HLO ops (XLA does not contract across HLO ops).
    return __fadd_rn(__fmul_rn(tau, m), ic);
#endif
}

// Full time loop for one element. TT=0 means runtime trip count.
template <int TT>
__device__ __forceinline__ void lif_elem(float ic, float tau, float thr, int T,
                                         float& m_out, int& s_out) {
    float m = 0.0f;
    int s = 0;
    if (TT > 0) {
#pragma unroll
        for (int t = 0; t < TT; ++t) {
            m = step_madd(tau, m, ic);
            if (m >= thr) { m = __fsub_rn(m, thr); ++s; }
        }
    } else {
        for (int t = 0; t < T; ++t) {
            m = step_madd(tau, m, ic);
            if (m >= thr) { m = __fsub_rn(m, thr); ++s; }
        }
    }
    m_out = m;
    s_out = s;
}

__global__ __launch_bounds__(256) void lif_fwd(
    const f32x4* __restrict__ x4,
    const float* __restrict__ thr_p,
    const float* __restrict__ tau_p,
    const int* __restrict__ ts_p,
    f32x4* __restrict__ ssum4,
    f32x4* __restrict__ mem4,
    unsigned int* __restrict__ total_spikes,
    int n4)
{
    const float thr  = thr_p[0];
    const float traw = tau_p[0];
    const int   T    = ts_p[0];

    // tau = sigmoid(traw). XLA's LogisticExpander: 1/(1+exp(-x)); on AMD, XLA's
    // exp lowers to __ocml_exp_f32 == HIP expf(). IEEE f32 divide matches XLA's
    // correctly-rounded fdiv. Goal: bit-exact tau vs the JAX reference.
    const float e   = expf(-traw);
    const float tau = __fdiv_rn(1.0f, __fadd_rn(1.0f, e));
    const float tF  = (float)T;

    unsigned int cnt = 0;
    const int stride = gridDim.x * blockDim.x;
    for (int i = blockIdx.x * blockDim.x + threadIdx.x; i < n4; i += stride) {
        const f32x4 xv = x4[i];
        float ic[4];
        // x / T: T=8 is a power of two -> exact scaling, any RN divide matches.
#pragma unroll
        for (int j = 0; j < 4; ++j) ic[j] = __fdiv_rn(xv[j], tF);

        float m[4];
        int   s[4];
        if (T == 8) {
#pragma unroll
            for (int j = 0; j < 4; ++j) lif_elem<8>(ic[j], tau, thr, T, m[j], s[j]);
        } else {
#pragma unroll
            for (int j = 0; j < 4; ++j) lif_elem<0>(ic[j], tau, thr, T, m[j], s[j]);
        }

        // Streaming outputs, never re-read here: non-temporal hint.
        f32x4 sv = { (float)s[0], (float)s[1], (float)s[2], (float)s[3] };
        f32x4 mv = { m[0], m[1], m[2], m[3] };
        __builtin_nontemporal_store(sv, &ssum4[i]);
        __builtin_nontemporal_store(mv, &mem4[i]);
        cnt += (unsigned int)(s[0] + s[1] + s[2] + s[3]);
    }

    // Exact integer reduction: wave64 shuffle reduce -> LDS -> one atomic/block.
    int c = (int)cnt;
    for (int off = 32; off > 0; off >>= 1)
        c += __shfl_down(c, off, 64);
    __shared__ unsigned int wred[4];  // 256 threads / 64 lanes
    const int lane = threadIdx.x & 63;
    const int wid  = threadIdx.x >> 6;
    if (lane == 0) wred[wid] = (unsigned int)c;
    __syncthreads();
    if (threadIdx.x == 0)
        atomicAdd(total_spikes, wred[0] + wred[1] + wred[2] + wred[3]);
}

__global__ void lif_finalize(const unsigned int* __restrict__ total_spikes,
                             const int* __restrict__ ts_p,
                             float* __restrict__ reg_out,
                             long long n)
{
    const int T = ts_p[0];
    // Exact integer total -> mean. n and T are powers of two, so the divides
    // are exact scalings; final ops in f32 like the reference.
    const double mean_d = (double)(*total_spikes) / (double)n;
    const float meanf = (float)mean_d;
    const float rate  = __fdiv_rn(meanf, (float)T);
    const float d     = __fsub_rn(rate, 0.5f);
    reg_out[0] = __fmul_rn(0.01f, __fmul_rn(d, d));
}

extern "C" void kernel_launch(void* const* d_in, const int* in_sizes, int n_in,
                              void* d_out, int out_size, void* d_ws, size_t ws_size,
                              hipStream_t stream) {
    const float* x   = (const float*)d_in[0];
    const float* thr = (const float*)d_in[1];
    const float* tau = (const float*)d_in[2];
    const int*   ts  = (const int*)d_in[3];
    const int N  = in_sizes[0];
    const int n4 = N / 4;  // N = 32*256*4096, divisible by 4

    float* ssum = (float*)d_out;
    float* mem  = ssum + (size_t)N;
    float* reg  = ssum + (size_t)2 * N;
    unsigned int* total = (unsigned int*)d_ws;

    (void)hipMemsetAsync(d_ws, 0, sizeof(unsigned int), stream);  // ws re-poisoned 0xAA

    const int block = 256;
    int grid = 2048;                       // ~8 blocks/CU, grid-stride the rest
    const int needed = (n4 + block - 1) / block;
    if (needed < grid) grid = needed;

    hipLaunchKernelGGL(lif_fwd, dim3(grid), dim3(block), 0, stream,
                       (const f32x4*)x, thr, tau, ts,
                       (f32x4*)ssum, (f32x4*)mem, total, n4);
    hipLaunchKernelGGL(lif_finalize, dim3(1), dim3(1), 0, stream,
                       total, ts, reg, (long long)N);
}

// Round 6
// 371.536 us; speedup vs baseline: 1.0049x; 1.0049x over previous
//
#include <hip/hip_runtime.h>
#include <math.h>

// Native clang vector types (required for nontemporal builtins; also gives the
// backend a shot at packed v_pk_*_f32 VOP3P codegen).
typedef float f32x4 __attribute__((ext_vector_type(4)));

// Full time loop for 4 elements. TT=0 means runtime trip count.
// Bit-exactness contract vs the JAX reference (validated absmax=0.0 in R3):
//  - recurrence is RN-mul then RN-add, NO contraction (pragma below)
//  - spike = (m >= thr); soft reset m -= thr exactly when spike. We use
//    fma(-thr, spike, m): spike=1 -> RN(m - thr) (thr*1 exact, single round),
//    spike=0 -> m. Bit-identical to the branch.
template <int TT>
__device__ __forceinline__ void lif4(const f32x4 ic, const float tau, const float thr,
                                     const int T, f32x4& m_out, f32x4& s_out) {
#pragma clang fp contract(off)
    f32x4 m = {0.0f, 0.0f, 0.0f, 0.0f};
    f32x4 s = {0.0f, 0.0f, 0.0f, 0.0f};
    const f32x4 tau4  = {tau, tau, tau, tau};
    const f32x4 nthr4 = {-thr, -thr, -thr, -thr};
    if (TT > 0) {
#pragma unroll
        for (int t = 0; t < TT; ++t) {
            const f32x4 p = tau4 * m;   // RN mul
            m = p + ic;                 // RN add (not contracted)
            f32x4 sp;
#pragma unroll
            for (int j = 0; j < 4; ++j) sp[j] = (m[j] >= thr) ? 1.0f : 0.0f;
            m = __builtin_elementwise_fma(nthr4, sp, m);
            s = s + sp;                 // exact small-integer adds
        }
    } else {
        for (int t = 0; t < T; ++t) {
            const f32x4 p = tau4 * m;
            m = p + ic;
            f32x4 sp;
#pragma unroll
            for (int j = 0; j < 4; ++j) sp[j] = (m[j] >= thr) ? 1.0f : 0.0f;
            m = __builtin_elementwise_fma(nthr4, sp, m);
            s = s + sp;
        }
    }
    m_out = m;
    s_out = s;
}

__global__ __launch_bounds__(256) void lif_fwd(
    const float* __restrict__ x,
    const float* __restrict__ thr_p,
    const float* __restrict__ tau_p,
    const int* __restrict__ ts_p,
    float* __restrict__ ssum,
    float* __restrict__ mem,
    float* __restrict__ partials,   // d_ws: one float per block, plain store (no init)
    int n4, int ntail)
{
#pragma clang fp contract(off)
    const float thr  = thr_p[0];
    const float traw = tau_p[0];
    const int   T    = ts_p[0];

    // tau = sigmoid(traw) = 1/(1+expf(-traw)); expf == __ocml_exp_f32, the same
    // libm XLA's exp lowers to on AMD -> bit-exact tau (validated absmax=0.0).
    const float e   = expf(-traw);
    const float tau = __fdiv_rn(1.0f, __fadd_rn(1.0f, e));
    const float tF  = (float)T;
    const bool  pw2 = T > 0 && (T & (T - 1)) == 0;
    // For power-of-two T, x*(1/T) is bit-identical to x/T (exponent shift,
    // identical RN result incl. subnormals). Saves the per-element fdiv.
    const float rT  = __fdiv_rn(1.0f, tF);

    const f32x4* __restrict__ x4 = (const f32x4*)x;
    f32x4* __restrict__ ssum4 = (f32x4*)ssum;
    f32x4* __restrict__ mem4  = (f32x4*)mem;

    float cnt = 0.0f;
    const int gtid   = blockIdx.x * blockDim.x + threadIdx.x;
    const int stride = gridDim.x * blockDim.x;

    // Tail elements (N not divisible by 4) — N=32*256*4096 here, so ntail==0.
    if (gtid < ntail) {
        const int idx = n4 * 4 + gtid;
        const float icv = pw2 ? __fmul_rn(x[idx], rT) : __fdiv_rn(x[idx], tF);
        float m = 0.0f, sf = 0.0f;
        for (int t = 0; t < T; ++t) {
            m = __fadd_rn(__fmul_rn(tau, m), icv);
            if (m >= thr) { m = __fsub_rn(m, thr); sf += 1.0f; }
        }
        ssum[idx] = sf; mem[idx] = m; cnt += sf;
    }

    const f32x4 rT4 = {rT, rT, rT, rT};
    for (int i = gtid; i < n4; i += stride) {
        const f32x4 xv = x4[i];
        f32x4 ic;
        if (pw2) {
            ic = xv * rT4;              // exact pow2 scaling
        } else {
#pragma unroll
            for (int j = 0; j < 4; ++j) ic[j] = __fdiv_rn(xv[j], tF);
        }

        f32x4 m, s;
        if (T == 8) lif4<8>(ic, tau, thr, T, m, s);
        else        lif4<0>(ic, tau, thr, T, m, s);

        // Streaming outputs, never re-read: non-temporal stores.
        __builtin_nontemporal_store(s, &ssum4[i]);
        __builtin_nontemporal_store(m, &mem4[i]);
        cnt += s[0] + s[1] + s[2] + s[3];   // exact: integers << 2^24
    }

    // Exact block reduction (all values small integers in f32):
    // wave64 shuffle -> LDS -> one plain store per block. No atomics, no init.
    float c = cnt;
    for (int off = 32; off > 0; off >>= 1)
        c += __shfl_down(c, off, 64);
    __shared__ float wred[4];           // 256 threads / 64 lanes
    const int lane = threadIdx.x & 63;
    const int wid  = threadIdx.x >> 6;
    if (lane == 0) wred[wid] = c;
    __syncthreads();
    if (threadIdx.x == 0)
        partials[blockIdx.x] = wred[0] + wred[1] + wred[2] + wred[3];
}

__global__ __launch_bounds__(256) void lif_finalize(
    const float* __restrict__ partials, int nparts,
    const int* __restrict__ ts_p,
    float* __restrict__ reg_out, long long n)
{
    const int T = ts_p[0];
    double acc = 0.0;
    for (int i = threadIdx.x; i < nparts; i += 256)
        acc += (double)partials[i];     // partials are exact integers < 2^17
    for (int off = 32; off > 0; off >>= 1)
        acc += __shfl_down(acc, off, 64);
    __shared__ double dred[4];
    const int lane = threadIdx.x & 63;
    const int wid  = threadIdx.x >> 6;
    if (lane == 0) dred[wid] = acc;
    __syncthreads();
    if (threadIdx.x == 0) {
        const double total  = dred[0] + dred[1] + dred[2] + dred[3];
        // Exact-integer total -> RN divides reproduces XLA's exact f32 tree-sum
        // mean bit-exactly (validated absmax=0.0 in R3).
        const double mean_d = total / (double)n;
        const float  meanf  = (float)mean_d;
        const float  rate   = __fdiv_rn(meanf, (float)T);
        const float  d      = __fsub_rn(rate, 0.5f);
        reg_out[0] = __fmul_rn(0.01f, __fmul_rn(d, d));
    }
}

extern "C" void kernel_launch(void* const* d_in, const int* in_sizes, int n_in,
                              void* d_out, int out_size, void* d_ws, size_t ws_size,
                              hipStream_t stream) {
    const float* x   = (const float*)d_in[0];
    const float* thr = (const float*)d_in[1];
    const float* tau = (const float*)d_in[2];
    const int*   ts  = (const int*)d_in[3];
    const int N     = in_sizes[0];
    const int n4    = N / 4;
    const int ntail = N - n4 * 4;

    float* ssum = (float*)d_out;
    float* mem  = ssum + (size_t)N;
    float* reg  = ssum + (size_t)2 * N;
    float* partials = (float*)d_ws;     // grid floats of scratch; no init needed

    const int block = 256;
    int grid = (n4 + block - 1) / block;
    if (grid > 2048) grid = 2048;       // ~8 blocks/CU, grid-stride the rest
    if (grid < 1)    grid = 1;

    hipLaunchKernelGGL(lif_fwd, dim3(grid), dim3(block), 0, stream,
                       x, thr, tau, ts, ssum, mem, partials, n4, ntail);
    hipLaunchKernelGGL(lif_finalize, dim3(1), dim3(block), 0, stream,
                       partials, grid, ts, reg, (long long)N);
}

// Round 8
// 370.373 us; speedup vs baseline: 1.0080x; 1.0031x over previous
//
#include <hip/hip_runtime.h>
#include <math.h>

// Native clang vector type (required for __builtin_nontemporal_store).
typedef float f32x4 __attribute__((ext_vector_type(4)));

// R3-exact scalar time loop (validated absmax=0.0 in R3): RN mul then RN add,
// no contraction, branchy soft reset via __fsub_rn, integer spike count.
// DO NOT rewrite into packed-vector/fma form: the R4/R6 "bit-identical"
// vectorization produced absmax=2^-8 (near-threshold spike-timing flip).
template <int TT>
__device__ __forceinline__ void lif_elem(float ic, float tau, float thr, int T,
                                         float& m_out, int& s_out) {
    float m = 0.0f;
    int s = 0;
    if (TT > 0) {
#pragma unroll
        for (int t = 0; t < TT; ++t) {
            m = __fadd_rn(__fmul_rn(tau, m), ic);
            if (m >= thr) { m = __fsub_rn(m, thr); ++s; }
        }
    } else {
        for (int t = 0; t < T; ++t) {
            m = __fadd_rn(__fmul_rn(tau, m), ic);
            if (m >= thr) { m = __fsub_rn(m, thr); ++s; }
        }
    }
    m_out = m;
    s_out = s;
}

__global__ __launch_bounds__(256) void lif_fwd(
    const float* __restrict__ x,
    const float* __restrict__ thr_p,
    const float* __restrict__ tau_p,
    const int* __restrict__ ts_p,
    float* __restrict__ ssum,
    float* __restrict__ mem,
    float* __restrict__ partials,   // d_ws: one float per block, plain store (no init)
    int n4, int ntail)
{
    const float thr  = thr_p[0];
    const float traw = tau_p[0];
    const int   T    = ts_p[0];

    // tau = sigmoid(traw) = 1/(1+expf(-traw)); expf == __ocml_exp_f32, the same
    // libm XLA's exp lowers to on AMD -> bit-exact tau (validated absmax=0.0 R3).
    const float e   = expf(-traw);
    const float tau = __fdiv_rn(1.0f, __fadd_rn(1.0f, e));
    const float tF  = (float)T;

    const f32x4* __restrict__ x4 = (const f32x4*)x;
    f32x4* __restrict__ ssum4 = (f32x4*)ssum;
    f32x4* __restrict__ mem4  = (f32x4*)mem;

    unsigned int cnt = 0;
    const int gtid   = blockIdx.x * blockDim.x + threadIdx.x;
    const int stride = gridDim.x * blockDim.x;

    // Tail elements (N not divisible by 4) — N=32*256*4096 here, so ntail==0.
    if (gtid < ntail) {
        const int idx = n4 * 4 + gtid;
        const float icv = __fdiv_rn(x[idx], tF);
        float m; int s;
        lif_elem<0>(icv, tau, thr, T, m, s);
        ssum[idx] = (float)s; mem[idx] = m; cnt += (unsigned int)s;
    }

    // Latency-bound fix: 4 independent iterations in flight (4x 16B loads).
#pragma unroll 4
    for (int i = gtid; i < n4; i += stride) {
        const f32x4 xv = x4[i];
        float ic[4];
#pragma unroll
        for (int j = 0; j < 4; ++j) ic[j] = __fdiv_rn(xv[j], tF);  // R3-exact

        float m[4];
        int   s[4];
        if (T == 8) {
#pragma unroll
            for (int j = 0; j < 4; ++j) lif_elem<8>(ic[j], tau, thr, T, m[j], s[j]);
        } else {
#pragma unroll
            for (int j = 0; j < 4; ++j) lif_elem<0>(ic[j], tau, thr, T, m[j], s[j]);
        }

        // Streaming outputs, never re-read: non-temporal stores (validated R3).
        f32x4 sv = { (float)s[0], (float)s[1], (float)s[2], (float)s[3] };
        f32x4 mv = { m[0], m[1], m[2], m[3] };
        __builtin_nontemporal_store(sv, &ssum4[i]);
        __builtin_nontemporal_store(mv, &mem4[i]);
        cnt += (unsigned int)(s[0] + s[1] + s[2] + s[3]);
    }

    // Exact integer block reduction: wave64 shuffle -> LDS -> one store/block.
    int c = (int)cnt;
    for (int off = 32; off > 0; off >>= 1)
        c += __shfl_down(c, off, 64);
    __shared__ int wred[4];             // 256 threads / 64 lanes
    const int lane = threadIdx.x & 63;
    const int wid  = threadIdx.x >> 6;
    if (lane == 0) wred[wid] = c;
    __syncthreads();
    if (threadIdx.x == 0)
        partials[blockIdx.x] = (float)(wred[0] + wred[1] + wred[2] + wred[3]);
}

__global__ __launch_bounds__(256) void lif_finalize(
    const float* __restrict__ partials, int nparts,
    const int* __restrict__ ts_p,
    float* __restrict__ reg_out, long long n)
{
    const int T = ts_p[0];
    double acc = 0.0;
    for (int i = threadIdx.x; i < nparts; i += 256)
        acc += (double)partials[i];     // partials are exact integers < 2^18
    for (int off = 32; off > 0; off >>= 1)
        acc += __shfl_down(acc, off, 64);
    __shared__ double dred[4];
    const int lane = threadIdx.x & 63;
    const int wid  = threadIdx.x >> 6;
    if (lane == 0) dred[wid] = acc;
    __syncthreads();
    if (threadIdx.x == 0) {
        const double total  = dred[0] + dred[1] + dred[2] + dred[3];
        // Exact-integer total; n, T are powers of two -> exact scalings; XLA's
        // f32 tree-sum of small integers is exact -> bit-exact reg_loss.
        const double mean_d = total / (double)n;
        const float  meanf  = (float)mean_d;
        const float  rate   = __fdiv_rn(meanf, (float)T);
        const float  d      = __fsub_rn(rate, 0.5f);
        reg_out[0] = __fmul_rn(0.01f, __fmul_rn(d, d));
    }
}

extern "C" void kernel_launch(void* const* d_in, const int* in_sizes, int n_in,
                              void* d_out, int out_size, void* d_ws, size_t ws_size,
                              hipStream_t stream) {
    const float* x   = (const float*)d_in[0];
    const float* thr = (const float*)d_in[1];
    const float* tau = (const float*)d_in[2];
    const int*   ts  = (const int*)d_in[3];
    const int N     = in_sizes[0];
    const int n4    = N / 4;
    const int ntail = N - n4 * 4;

    float* ssum = (float*)d_out;
    float* mem  = ssum + (size_t)N;
    float* reg  = ssum + (size_t)2 * N;
    float* partials = (float*)d_ws;     // grid floats of scratch; no init needed

    const int block = 256;
    int grid = (n4 + block - 1) / block;
    if (grid > 2048) grid = 2048;       // ~8 blocks/CU, grid-stride the rest
    if (grid < 1)    grid = 1;

    hipLaunchKernelGGL(lif_fwd, dim3(grid), dim3(block), 0, stream,
                       x, thr, tau, ts, ssum, mem, partials, n4, ntail);
    hipLaunchKernelGGL(lif_finalize, dim3(1), dim3(block), 0, stream,
                       partials, grid, ts, reg, (long long)N);
}

// Round 10
// 366.843 us; speedup vs baseline: 1.0177x; 1.0096x over previous
//
#include <hip/hip_runtime.h>
#include <math.h>

typedef float f32x4 __attribute__((ext_vector_type(4)));

// R3/R8-exact scalar time loop (validated absmax=0.0): RN mul then RN add,
// no contraction, branchy soft reset via __fsub_rn, integer spike count.
// DO NOT rewrite into packed-vector/fma form: the R4/R6 vectorization
// produced absmax=2^-8 (near-threshold spike-timing flip).
template <int TT>
__device__ __forceinline__ void lif_elem(float ic, float tau, float thr, int T,
                                         float& m_out, int& s_out) {
    float m = 0.0f;
    int s = 0;
    if (TT > 0) {
#pragma unroll
        for (int t = 0; t < TT; ++t) {
            m = __fadd_rn(__fmul_rn(tau, m), ic);
            if (m >= thr) { m = __fsub_rn(m, thr); ++s; }
        }
    } else {
        for (int t = 0; t < T; ++t) {
            m = __fadd_rn(__fmul_rn(tau, m), ic);
            if (m >= thr) { m = __fsub_rn(m, thr); ++s; }
        }
    }
    m_out = m;
    s_out = s;
}

__global__ __launch_bounds__(256) void lif_fwd(
    const float* __restrict__ x,
    const float* __restrict__ thr_p,
    const float* __restrict__ tau_p,
    const int* __restrict__ ts_p,
    float* __restrict__ ssum,
    float* __restrict__ mem,
    float* __restrict__ partials,   // d_ws: one float per block, plain store (no init)
    int n4, int ntail)
{
    const float thr  = thr_p[0];
    const float traw = tau_p[0];
    const int   T    = ts_p[0];

    // tau = sigmoid(traw) = 1/(1+expf(-traw)); expf == __ocml_exp_f32, the same
    // libm XLA's exp lowers to on AMD -> bit-exact tau (validated absmax=0.0).
    const float e   = expf(-traw);
    const float tau = __fdiv_rn(1.0f, __fadd_rn(1.0f, e));
    const float tF  = (float)T;

    const f32x4* __restrict__ x4 = (const f32x4*)x;
    f32x4* __restrict__ ssum4 = (f32x4*)ssum;
    f32x4* __restrict__ mem4  = (f32x4*)mem;

    unsigned int cnt = 0;
    const int gtid   = blockIdx.x * blockDim.x + threadIdx.x;
    const int stride = gridDim.x * blockDim.x;

    // Tail elements (N not divisible by 4) — N=32*256*4096 here, so ntail==0.
    if (gtid < ntail) {
        const int idx = n4 * 4 + gtid;
        const float icv = __fdiv_rn(x[idx], tF);
        float m; int s;
        lif_elem<0>(icv, tau, thr, T, m, s);
        ssum[idx] = (float)s; mem[idx] = m; cnt += (unsigned int)s;
    }

#pragma unroll 4
    for (int i = gtid; i < n4; i += stride) {
        const f32x4 xv = x4[i];
        float ic[4];
#pragma unroll
        for (int j = 0; j < 4; ++j) ic[j] = __fdiv_rn(xv[j], tF);  // R3-exact

        float m[4];
        int   s[4];
        if (T == 8) {
#pragma unroll
            for (int j = 0; j < 4; ++j) lif_elem<8>(ic[j], tau, thr, T, m[j], s[j]);
        } else {
#pragma unroll
            for (int j = 0; j < 4; ++j) lif_elem<0>(ic[j], tau, thr, T, m[j], s[j]);
        }

        // R9 single lever: REGULAR stores (nt removed). The harness fill
        // kernels sustain 6.5 TB/s with regular stores; testing whether the
        // nt path was throttling our two 128MB write streams.
        f32x4 sv = { (float)s[0], (float)s[1], (float)s[2], (float)s[3] };
        f32x4 mv = { m[0], m[1], m[2], m[3] };
        ssum4[i] = sv;
        mem4[i]  = mv;
        cnt += (unsigned int)(s[0] + s[1] + s[2] + s[3]);
    }

    // Exact integer block reduction: wave64 shuffle -> LDS -> one store/block.
    int c = (int)cnt;
    for (int off = 32; off > 0; off >>= 1)
        c += __shfl_down(c, off, 64);
    __shared__ int wred[4];             // 256 threads / 64 lanes
    const int lane = threadIdx.x & 63;
    const int wid  = threadIdx.x >> 6;
    if (lane == 0) wred[wid] = c;
    __syncthreads();
    if (threadIdx.x == 0)
        partials[blockIdx.x] = (float)(wred[0] + wred[1] + wred[2] + wred[3]);
}

__global__ __launch_bounds__(256) void lif_finalize(
    const float* __restrict__ partials, int nparts,
    const int* __restrict__ ts_p,
    float* __restrict__ reg_out, long long n)
{
    const int T = ts_p[0];
    double acc = 0.0;
    for (int i = threadIdx.x; i < nparts; i += 256)
        acc += (double)partials[i];     // partials are exact integers < 2^18
    for (int off = 32; off > 0; off >>= 1)
        acc += __shfl_down(acc, off, 64);
    __shared__ double dred[4];
    const int lane = threadIdx.x & 63;
    const int wid  = threadIdx.x >> 6;
    if (lane == 0) dred[wid] = acc;
    __syncthreads();
    if (threadIdx.x == 0) {
        const double total  = dred[0] + dred[1] + dred[2] + dred[3];
        // Exact-integer total; n, T are powers of two -> exact scalings; XLA's
        // f32 tree-sum of small integers is exact -> bit-exact reg_loss.
        const double mean_d = total / (double)n;
        const float  meanf  = (float)mean_d;
        const float  rate   = __fdiv_rn(meanf, (float)T);
        const float  d      = __fsub_rn(rate, 0.5f);
        reg_out[0] = __fmul_rn(0.01f, __fmul_rn(d, d));
    }
}

extern "C" void kernel_launch(void* const* d_in, const int* in_sizes, int n_in,
                              void* d_out, int out_size, void* d_ws, size_t ws_size,
                              hipStream_t stream) {
    const float* x   = (const float*)d_in[0];
    const float* thr = (const float*)d_in[1];
    const float* tau = (const float*)d_in[2];
    const int*   ts  = (const int*)d_in[3];
    const int N     = in_sizes[0];
    const int n4    = N / 4;
    const int ntail = N - n4 * 4;

    float* ssum = (float*)d_out;
    float* mem  = ssum + (size_t)N;
    float* reg  = ssum + (size_t)2 * N;
    float* partials = (float*)d_ws;     // grid floats of scratch; no init needed

    const int block = 256;
    int grid = (n4 + block - 1) / block;
    if (grid > 2048) grid = 2048;       // ~8 blocks/CU, grid-stride the rest
    if (grid < 1)    grid = 1;

    hipLaunchKernelGGL(lif_fwd, dim3(grid), dim3(block), 0, stream,
                       x, thr, tau, ts, ssum, mem, partials, n4, ntail);
    hipLaunchKernelGGL(lif_finalize, dim3(1), dim3(block), 0, stream,
                       partials, grid, ts, reg, (long long)N);
}